// Round 2
// baseline (158.300 us; speedup 1.0000x reference)
//
#include <hip/hip_runtime.h>
#include <math.h>

#define HW_   6688      // 44*152
#define W_    152
#define NPIX  107008    // 16*44*152
#define OW_   1216      // 152*8
#define OHW_  428032    // 352*1216

// transposed-weight offsets (floats) inside d_ws, layout [cin][cout]
#define OFF_W0 0        // 128*64
#define OFF_W1 8192     // 64*32
#define OFF_W2 10240    // 32*16
#define OFF_W3 10752    // 16*8
#define OFF_W4 10880    // 8*4
#define OFF_CW 10912    // 4*3

__device__ __forceinline__ float fast_sigmoid(float x) {
    return __builtin_amdgcn_rcpf(1.0f + __expf(-x));
}
__device__ __forceinline__ float eluf(float x) {
    return x > 0.0f ? x : (__expf(x) - 1.0f);
}

// Transpose all weights (cout,cin) -> (cin,cout) into workspace.
__global__ void prep_weights(const float* __restrict__ w0, const float* __restrict__ w1,
                             const float* __restrict__ w2, const float* __restrict__ w3,
                             const float* __restrict__ w4, const float* __restrict__ cw,
                             float* __restrict__ ws) {
    int t = blockIdx.x * blockDim.x + threadIdx.x;
    int stride = gridDim.x * blockDim.x;
    for (int i = t; i < 64 * 128; i += stride) { int o = i >> 7, c = i & 127; ws[OFF_W0 + c * 64 + o] = w0[i]; }
    for (int i = t; i < 32 * 64;  i += stride) { int o = i >> 6, c = i & 63;  ws[OFF_W1 + c * 32 + o] = w1[i]; }
    for (int i = t; i < 16 * 32;  i += stride) { int o = i >> 5, c = i & 31;  ws[OFF_W2 + c * 16 + o] = w2[i]; }
    for (int i = t; i < 8 * 16;   i += stride) { int o = i >> 4, c = i & 15;  ws[OFF_W3 + c * 8  + o] = w3[i]; }
    for (int i = t; i < 4 * 8;    i += stride) { int o = i >> 3, c = i & 7;   ws[OFF_W4 + c * 4  + o] = w4[i]; }
    for (int i = t; i < 3 * 4;    i += stride) { int o = i >> 2, c = i & 3;   ws[OFF_CW + c * 3  + o] = cw[i]; }
}

// 64 pixels per block, 4 wave-slices; wave s computes output quarter s of each
// layer. Activations exchanged via padded LDS (conflict-free odd strides).
__global__ __launch_bounds__(256, 4)
void lpg_fused(const float* __restrict__ x, const float* __restrict__ wt,
               const float* __restrict__ b0, const float* __restrict__ b1,
               const float* __restrict__ b2, const float* __restrict__ b3,
               const float* __restrict__ b4, const float* __restrict__ cb,
               float* __restrict__ out) {
    __shared__ float A[64 * 65];   // 16.6 KB: a0 (stride 65), later a2 (17), a4 (5)
    __shared__ float Bs[64 * 33];  //  8.4 KB: a1 (stride 33), later a3 (9)

    const int tid = threadIdx.x;
    const int s   = tid >> 6;      // slice == wave id (wave-uniform)
    const int p   = tid & 63;      // pixel within block
    const int pix = blockIdx.x * 64 + p;
    const int b   = pix / HW_;
    const int hw  = pix - b * HW_;
    const int h   = hw / W_;
    const int w   = hw - h * W_;
    const float* xg = x + (size_t)b * 128 * HW_ + hw;

    // ---- layer 0: 128 -> 64, this wave computes outputs [s*16, s*16+16)
    {
        const float* w0t = wt + OFF_W0 + s * 16;
        float acc[16];
#pragma unroll
        for (int j = 0; j < 16; ++j) acc[j] = b0[s * 16 + j];
        for (int cc = 0; cc < 128; cc += 8) {
            float xv[8];
#pragma unroll
            for (int k = 0; k < 8; ++k) xv[k] = xg[(size_t)(cc + k) * HW_];
#pragma unroll
            for (int k = 0; k < 8; ++k) {
                const float* wr = w0t + (cc + k) * 64;
#pragma unroll
                for (int j = 0; j < 16; ++j) acc[j] = fmaf(wr[j], xv[k], acc[j]);
            }
        }
#pragma unroll
        for (int j = 0; j < 16; ++j) A[p * 65 + s * 16 + j] = eluf(acc[j]);
    }
    __syncthreads();

    // ---- layer 1: 64 -> 32, outputs [s*8, s*8+8)
    {
        const float* w1t = wt + OFF_W1 + s * 8;
        float a1[8];
#pragma unroll
        for (int j = 0; j < 8; ++j) a1[j] = b1[s * 8 + j];
#pragma unroll
        for (int c = 0; c < 64; ++c) {
            float v = A[p * 65 + c];
#pragma unroll
            for (int j = 0; j < 8; ++j) a1[j] = fmaf(w1t[c * 32 + j], v, a1[j]);
        }
#pragma unroll
        for (int j = 0; j < 8; ++j) Bs[p * 33 + s * 8 + j] = eluf(a1[j]);
    }
    __syncthreads();

    // ---- layer 2: 32 -> 16, outputs [s*4, s*4+4)  (writes A, stride 17)
    {
        const float* w2t = wt + OFF_W2 + s * 4;
        float a2[4];
#pragma unroll
        for (int j = 0; j < 4; ++j) a2[j] = b2[s * 4 + j];
#pragma unroll
        for (int c = 0; c < 32; ++c) {
            float v = Bs[p * 33 + c];
#pragma unroll
            for (int j = 0; j < 4; ++j) a2[j] = fmaf(w2t[c * 16 + j], v, a2[j]);
        }
#pragma unroll
        for (int j = 0; j < 4; ++j) A[p * 17 + s * 4 + j] = eluf(a2[j]);
    }
    __syncthreads();

    // ---- layer 3: 16 -> 8, outputs [s*2, s*2+2)  (writes Bs, stride 9)
    {
        const float* w3t = wt + OFF_W3 + s * 2;
        float a3[2];
#pragma unroll
        for (int j = 0; j < 2; ++j) a3[j] = b3[s * 2 + j];
#pragma unroll
        for (int c = 0; c < 16; ++c) {
            float v = A[p * 17 + c];
#pragma unroll
            for (int j = 0; j < 2; ++j) a3[j] = fmaf(w3t[c * 8 + j], v, a3[j]);
        }
#pragma unroll
        for (int j = 0; j < 2; ++j) Bs[p * 9 + s * 2 + j] = eluf(a3[j]);
    }
    __syncthreads();

    // ---- layer 4: 8 -> 4, output s  (writes A, stride 5)
    {
        const float* w4t = wt + OFF_W4 + s;
        float a4 = b4[s];
#pragma unroll
        for (int c = 0; c < 8; ++c) a4 = fmaf(w4t[c * 4], Bs[p * 9 + c], a4);
        A[p * 5 + s] = eluf(a4);
    }
    __syncthreads();

    // ---- head 4 -> 3 + plane params (redundant across the 4 slices; cheap)
    const float* cwt = wt + OFF_CW;
    float v0 = A[p * 5 + 0], v1 = A[p * 5 + 1], v2 = A[p * 5 + 2], v3 = A[p * 5 + 3];
    float y0 = cb[0], y1 = cb[1], y2 = cb[2];
    y0 = fmaf(cwt[0], v0, y0); y1 = fmaf(cwt[1], v0, y1); y2 = fmaf(cwt[2], v0, y2);
    y0 = fmaf(cwt[3], v1, y0); y1 = fmaf(cwt[4], v1, y1); y2 = fmaf(cwt[5], v1, y2);
    y0 = fmaf(cwt[6], v2, y0); y1 = fmaf(cwt[7], v2, y1); y2 = fmaf(cwt[8], v2, y2);
    y0 = fmaf(cwt[9], v3, y0); y1 = fmaf(cwt[10], v3, y1); y2 = fmaf(cwt[11], v3, y2);

    float theta = 0.5235987756f * fast_sigmoid(y0);   // pi/6
    float phi   = 6.2831853072f * fast_sigmoid(y1);   // 2*pi
    float dist  = 83.0f         * fast_sigmoid(y2);
    float st = __sinf(theta), ct = __cosf(theta);
    float sp = __sinf(phi),   cp = __cosf(phi);
    float n1 = st * cp, n2 = st * sp, n3 = ct;
    float inv = __frsqrt_rn(fmaf(n1, n1, fmaf(n2, n2, n3 * n3)));
    n1 *= inv; n2 *= inv; n3 *= inv;

    // ---- 8x8 depth expansion: this slice writes rows 2s and 2s+1
    const float ksc = 1.0f / (8.0f * 715.0f);
    float nu[8];
#pragma unroll
    for (int j = 0; j < 8; ++j) nu[j] = n1 * (((float)j - 3.5f) * ksc);
    const int obase = b * OHW_ + (h * 8) * OW_ + w * 8;
#pragma unroll
    for (int r = 0; r < 2; ++r) {
        int i = s * 2 + r;
        float base = fmaf(n2, ((float)i - 3.5f) * ksc, n3);
        float4 r0, r1;
        r0.x = dist * __builtin_amdgcn_rcpf(base + nu[0]);
        r0.y = dist * __builtin_amdgcn_rcpf(base + nu[1]);
        r0.z = dist * __builtin_amdgcn_rcpf(base + nu[2]);
        r0.w = dist * __builtin_amdgcn_rcpf(base + nu[3]);
        r1.x = dist * __builtin_amdgcn_rcpf(base + nu[4]);
        r1.y = dist * __builtin_amdgcn_rcpf(base + nu[5]);
        r1.z = dist * __builtin_amdgcn_rcpf(base + nu[6]);
        r1.w = dist * __builtin_amdgcn_rcpf(base + nu[7]);
        float4* op = (float4*)(out + obase + i * OW_);
        op[0] = r0;
        op[1] = r1;
    }
}

extern "C" void kernel_launch(void* const* d_in, const int* in_sizes, int n_in,
                              void* d_out, int out_size, void* d_ws, size_t ws_size,
                              hipStream_t stream) {
    const float* x  = (const float*)d_in[0];
    const float* w0 = (const float*)d_in[1];
    const float* b0 = (const float*)d_in[2];
    const float* w1 = (const float*)d_in[3];
    const float* b1 = (const float*)d_in[4];
    const float* w2 = (const float*)d_in[5];
    const float* b2 = (const float*)d_in[6];
    const float* w3 = (const float*)d_in[7];
    const float* b3 = (const float*)d_in[8];
    const float* w4 = (const float*)d_in[9];
    const float* b4 = (const float*)d_in[10];
    const float* cw = (const float*)d_in[11];
    const float* cb = (const float*)d_in[12];
    float* ws  = (float*)d_ws;
    float* out = (float*)d_out;

    prep_weights<<<16, 256, 0, stream>>>(w0, w1, w2, w3, w4, cw, ws);
    lpg_fused<<<NPIX / 64, 256, 0, stream>>>(x, ws, b0, b1, b2, b3, b4, cb, out);
}

// Round 3
// 92.551 us; speedup vs baseline: 1.7104x; 1.7104x over previous
//
#include <hip/hip_runtime.h>
#include <math.h>

#define HW_   6688      // 44*152
#define W_    152
#define NPIX  107008    // 16*44*152
#define OW_   1216      // 152*8
#define OHW_  428032    // 352*1216

// transposed-weight offsets (floats) inside d_ws, layout [cin][cout]
#define OFF_W0 0        // 128*64
#define OFF_W1 8192     // 64*32
#define OFF_W2 10240    // 32*16
#define OFF_W3 10752    // 16*8
#define OFF_W4 10880    // 8*4
#define OFF_CW 10912    // 4*3

// LDS float offsets (S has 8192 floats = 32 KB; x-tile overlaid then reused)
#define L_A0 0          // stride 65: 64*65 = 4160   (overwrites x-tile, barriered)
#define L_A1 4160       // stride 33: 64*33 = 2112 -> 6272
#define L_A2 6272       // stride 17: 64*17 = 1088 -> 7360
#define L_A3 7360       // stride 9:  64*9  = 576  -> 7936
#define L_A4 0          // stride 5:  64*5  = 320   (a0 region dead by then)

__device__ __forceinline__ float fast_sigmoid(float x) {
    return __builtin_amdgcn_rcpf(1.0f + __expf(-x));
}
__device__ __forceinline__ float eluf(float x) {
    return x > 0.0f ? x : (__expf(x) - 1.0f);
}

// Transpose all weights (cout,cin) -> (cin,cout) into workspace.
__global__ void prep_weights(const float* __restrict__ w0, const float* __restrict__ w1,
                             const float* __restrict__ w2, const float* __restrict__ w3,
                             const float* __restrict__ w4, const float* __restrict__ cw,
                             float* __restrict__ ws) {
    int t = blockIdx.x * blockDim.x + threadIdx.x;
    int stride = gridDim.x * blockDim.x;
    for (int i = t; i < 64 * 128; i += stride) { int o = i >> 7, c = i & 127; ws[OFF_W0 + c * 64 + o] = w0[i]; }
    for (int i = t; i < 32 * 64;  i += stride) { int o = i >> 6, c = i & 63;  ws[OFF_W1 + c * 32 + o] = w1[i]; }
    for (int i = t; i < 16 * 32;  i += stride) { int o = i >> 5, c = i & 31;  ws[OFF_W2 + c * 16 + o] = w2[i]; }
    for (int i = t; i < 8 * 16;   i += stride) { int o = i >> 4, c = i & 15;  ws[OFF_W3 + c * 8  + o] = w3[i]; }
    for (int i = t; i < 4 * 8;    i += stride) { int o = i >> 3, c = i & 7;   ws[OFF_W4 + c * 4  + o] = w4[i]; }
    for (int i = t; i < 3 * 4;    i += stride) { int o = i >> 2, c = i & 3;   ws[OFF_CW + c * 3  + o] = cw[i]; }
}

// 64 pixels/block, 4 waves; wave s computes output quarter s of each layer.
// s is readfirstlane'd -> all weight/bias loads are scalar s_loads.
// x-tile staged once into LDS (coalesced), activations via padded LDS.
__global__ __launch_bounds__(256, 5)
void lpg_fused(const float* __restrict__ x, const float* __restrict__ wt,
               const float* __restrict__ b0, const float* __restrict__ b1,
               const float* __restrict__ b2, const float* __restrict__ b3,
               const float* __restrict__ b4, const float* __restrict__ cb,
               float* __restrict__ out) {
    __shared__ float S[8192];   // exactly 32 KB -> 5 blocks/CU

    const int tid = threadIdx.x;
    const int s   = __builtin_amdgcn_readfirstlane(tid >> 6);  // wave slice, SGPR
    const int p   = tid & 63;      // pixel within block
    const int pix = blockIdx.x * 64 + p;
    const int b   = pix / HW_;
    const int hw  = pix - b * HW_;
    const int h   = hw / W_;
    const int w   = hw - h * W_;
    const float* xg = x + (size_t)b * (128 * HW_) + hw;

    // ---- stage x-tile: wave s loads channels [s*32, s*32+32) for 64 pixels
    {
        float xv[32];
#pragma unroll
        for (int k = 0; k < 32; ++k) xv[k] = xg[(size_t)(s * 32 + k) * HW_];
#pragma unroll
        for (int k = 0; k < 32; ++k) S[(s * 32 + k) * 64 + p] = xv[k];
    }
    __syncthreads();

    // ---- layer 0: 128 -> 64, this wave computes outputs [s*16, s*16+16)
    float acc[16];
    {
        const float* w0t = wt + OFF_W0 + s * 16;
#pragma unroll
        for (int j = 0; j < 16; ++j) acc[j] = b0[s * 16 + j];
#pragma unroll 8
        for (int c = 0; c < 128; ++c) {
            float v = S[c * 64 + p];
#pragma unroll
            for (int j = 0; j < 16; ++j) acc[j] = fmaf(w0t[c * 64 + j], v, acc[j]);
        }
    }
    __syncthreads();   // all waves done reading x-tile
#pragma unroll
    for (int j = 0; j < 16; ++j) S[L_A0 + p * 65 + s * 16 + j] = eluf(acc[j]);
    __syncthreads();

    // ---- layer 1: 64 -> 32, outputs [s*8, s*8+8)
    {
        const float* w1t = wt + OFF_W1 + s * 8;
        float a1[8];
#pragma unroll
        for (int j = 0; j < 8; ++j) a1[j] = b1[s * 8 + j];
#pragma unroll
        for (int c = 0; c < 64; ++c) {
            float v = S[L_A0 + p * 65 + c];
#pragma unroll
            for (int j = 0; j < 8; ++j) a1[j] = fmaf(w1t[c * 32 + j], v, a1[j]);
        }
#pragma unroll
        for (int j = 0; j < 8; ++j) S[L_A1 + p * 33 + s * 8 + j] = eluf(a1[j]);
    }
    __syncthreads();

    // ---- layer 2: 32 -> 16, outputs [s*4, s*4+4)
    {
        const float* w2t = wt + OFF_W2 + s * 4;
        float a2[4];
#pragma unroll
        for (int j = 0; j < 4; ++j) a2[j] = b2[s * 4 + j];
#pragma unroll
        for (int c = 0; c < 32; ++c) {
            float v = S[L_A1 + p * 33 + c];
#pragma unroll
            for (int j = 0; j < 4; ++j) a2[j] = fmaf(w2t[c * 16 + j], v, a2[j]);
        }
#pragma unroll
        for (int j = 0; j < 4; ++j) S[L_A2 + p * 17 + s * 4 + j] = eluf(a2[j]);
    }
    __syncthreads();

    // ---- layer 3: 16 -> 8, outputs [s*2, s*2+2)
    {
        const float* w3t = wt + OFF_W3 + s * 2;
        float a3[2];
#pragma unroll
        for (int j = 0; j < 2; ++j) a3[j] = b3[s * 2 + j];
#pragma unroll
        for (int c = 0; c < 16; ++c) {
            float v = S[L_A2 + p * 17 + c];
#pragma unroll
            for (int j = 0; j < 2; ++j) a3[j] = fmaf(w3t[c * 8 + j], v, a3[j]);
        }
#pragma unroll
        for (int j = 0; j < 2; ++j) S[L_A3 + p * 9 + s * 2 + j] = eluf(a3[j]);
    }
    __syncthreads();

    // ---- layer 4: 8 -> 4, output s
    {
        const float* w4t = wt + OFF_W4 + s;
        float a4 = b4[s];
#pragma unroll
        for (int c = 0; c < 8; ++c) a4 = fmaf(w4t[c * 4], S[L_A3 + p * 9 + c], a4);
        S[L_A4 + p * 5 + s] = eluf(a4);
    }
    __syncthreads();

    // ---- head 4 -> 3 + plane params (redundant across the 4 slices; cheap)
    const float* cwt = wt + OFF_CW;
    float v0 = S[L_A4 + p * 5 + 0], v1 = S[L_A4 + p * 5 + 1];
    float v2 = S[L_A4 + p * 5 + 2], v3 = S[L_A4 + p * 5 + 3];
    float y0 = cb[0], y1 = cb[1], y2 = cb[2];
    y0 = fmaf(cwt[0], v0, y0); y1 = fmaf(cwt[1], v0, y1); y2 = fmaf(cwt[2], v0, y2);
    y0 = fmaf(cwt[3], v1, y0); y1 = fmaf(cwt[4], v1, y1); y2 = fmaf(cwt[5], v1, y2);
    y0 = fmaf(cwt[6], v2, y0); y1 = fmaf(cwt[7], v2, y1); y2 = fmaf(cwt[8], v2, y2);
    y0 = fmaf(cwt[9], v3, y0); y1 = fmaf(cwt[10], v3, y1); y2 = fmaf(cwt[11], v3, y2);

    float theta = 0.5235987756f * fast_sigmoid(y0);   // pi/6
    float phi   = 6.2831853072f * fast_sigmoid(y1);   // 2*pi
    float dist  = 83.0f         * fast_sigmoid(y2);
    float st = __sinf(theta), ct = __cosf(theta);
    float sp = __sinf(phi),   cp = __cosf(phi);
    float n1 = st * cp, n2 = st * sp, n3 = ct;
    float inv = __frsqrt_rn(fmaf(n1, n1, fmaf(n2, n2, n3 * n3)));
    n1 *= inv; n2 *= inv; n3 *= inv;

    // ---- 8x8 depth expansion: this slice writes rows 2s and 2s+1
    const float ksc = 1.0f / (8.0f * 715.0f);
    float nu[8];
#pragma unroll
    for (int j = 0; j < 8; ++j) nu[j] = n1 * (((float)j - 3.5f) * ksc);
    const int obase = b * OHW_ + (h * 8) * OW_ + w * 8;
#pragma unroll
    for (int r = 0; r < 2; ++r) {
        int i = s * 2 + r;
        float base = fmaf(n2, ((float)i - 3.5f) * ksc, n3);
        float4 r0, r1;
        r0.x = dist * __builtin_amdgcn_rcpf(base + nu[0]);
        r0.y = dist * __builtin_amdgcn_rcpf(base + nu[1]);
        r0.z = dist * __builtin_amdgcn_rcpf(base + nu[2]);
        r0.w = dist * __builtin_amdgcn_rcpf(base + nu[3]);
        r1.x = dist * __builtin_amdgcn_rcpf(base + nu[4]);
        r1.y = dist * __builtin_amdgcn_rcpf(base + nu[5]);
        r1.z = dist * __builtin_amdgcn_rcpf(base + nu[6]);
        r1.w = dist * __builtin_amdgcn_rcpf(base + nu[7]);
        float4* op = (float4*)(out + obase + i * OW_);
        op[0] = r0;
        op[1] = r1;
    }
}

extern "C" void kernel_launch(void* const* d_in, const int* in_sizes, int n_in,
                              void* d_out, int out_size, void* d_ws, size_t ws_size,
                              hipStream_t stream) {
    const float* x  = (const float*)d_in[0];
    const float* w0 = (const float*)d_in[1];
    const float* b0 = (const float*)d_in[2];
    const float* w1 = (const float*)d_in[3];
    const float* b1 = (const float*)d_in[4];
    const float* w2 = (const float*)d_in[5];
    const float* b2 = (const float*)d_in[6];
    const float* w3 = (const float*)d_in[7];
    const float* b3 = (const float*)d_in[8];
    const float* w4 = (const float*)d_in[9];
    const float* b4 = (const float*)d_in[10];
    const float* cw = (const float*)d_in[11];
    const float* cb = (const float*)d_in[12];
    float* ws  = (float*)d_ws;
    float* out = (float*)d_out;

    prep_weights<<<16, 256, 0, stream>>>(w0, w1, w2, w3, w4, cw, ws);
    lpg_fused<<<NPIX / 64, 256, 0, stream>>>(x, ws, b0, b1, b2, b3, b4, cb, out);
}

// Round 4
// 90.197 us; speedup vs baseline: 1.7550x; 1.0261x over previous
//
#include <hip/hip_runtime.h>
#include <math.h>

#define HW_   6688      // 44*152
#define W_    152
#define NPIX  107008    // 16*44*152
#define OW_   1216      // 152*8
#define OHW_  428032    // 352*1216

// transposed-weight offsets (floats), layout [cin][cout] — used in d_ws AND LDS
#define NW     10924
#define OFF_W0 0        // 128*64
#define OFF_W1 8192     // 64*32
#define OFF_W2 10240    // 32*16
#define OFF_W3 10752    // 16*8
#define OFF_W4 10880    // 8*4
#define OFF_CW 10912    // 4*3

// LDS activation regions (floats), after the weight block
#define L_A0 10924      // stride 65: 64*65 = 4160
#define L_A1 15084      // stride 33: 64*33 = 2112
#define L_A2 17196      // stride 17: 64*17 = 1088
#define L_A3 18284      // stride 9 : 64*9  = 576
#define L_A4 18860      // stride 5 : 64*5  = 320
#define LDSF 19180      // 76,720 B -> 2 blocks/CU

__device__ __forceinline__ float fast_sigmoid(float x) {
    return __builtin_amdgcn_rcpf(1.0f + __expf(-x));
}
__device__ __forceinline__ float eluf(float x) {
    return x > 0.0f ? x : (__expf(x) - 1.0f);
}

// Transpose all weights (cout,cin) -> (cin,cout) into workspace.
__global__ void prep_weights(const float* __restrict__ w0, const float* __restrict__ w1,
                             const float* __restrict__ w2, const float* __restrict__ w3,
                             const float* __restrict__ w4, const float* __restrict__ cw,
                             float* __restrict__ ws) {
    int t = blockIdx.x * blockDim.x + threadIdx.x;
    int stride = gridDim.x * blockDim.x;
    for (int i = t; i < 64 * 128; i += stride) { int o = i >> 7, c = i & 127; ws[OFF_W0 + c * 64 + o] = w0[i]; }
    for (int i = t; i < 32 * 64;  i += stride) { int o = i >> 6, c = i & 63;  ws[OFF_W1 + c * 32 + o] = w1[i]; }
    for (int i = t; i < 16 * 32;  i += stride) { int o = i >> 5, c = i & 31;  ws[OFF_W2 + c * 16 + o] = w2[i]; }
    for (int i = t; i < 8 * 16;   i += stride) { int o = i >> 4, c = i & 15;  ws[OFF_W3 + c * 8  + o] = w3[i]; }
    for (int i = t; i < 4 * 8;    i += stride) { int o = i >> 3, c = i & 7;   ws[OFF_W4 + c * 4  + o] = w4[i]; }
    for (int i = t; i < 3 * 4;    i += stride) { int o = i >> 2, c = i & 3;   ws[OFF_CW + c * 3  + o] = cw[i]; }
}

// 64 pixels/block, 4 waves; wave s computes output quarter s of each layer.
// ALL weights live in LDS (uniform-address ds_read_b128 broadcasts) — no SMEM
// in any hot loop, so lgkmcnt stays in-order/countable. x read from global
// (vmcnt, in-order). Activations exchanged via padded LDS (conflict-free).
__global__ __launch_bounds__(256, 2)
void lpg_fused(const float* __restrict__ x, const float* __restrict__ wt,
               const float* __restrict__ b0, const float* __restrict__ b1,
               const float* __restrict__ b2, const float* __restrict__ b3,
               const float* __restrict__ b4, const float* __restrict__ cb,
               float* __restrict__ out) {
    __shared__ __align__(16) float S[LDSF];

    const int tid = threadIdx.x;
    // cooperative weight fill: 43 coalesced rounds of 1 KB/wave
    for (int i = tid; i < NW; i += 256) S[i] = wt[i];

    const int s   = __builtin_amdgcn_readfirstlane(tid >> 6);  // wave slice (SGPR)
    const int p   = tid & 63;
    const int pix = blockIdx.x * 64 + p;
    const int b   = pix / HW_;
    const int hw  = pix - b * HW_;
    const int h   = hw / W_;
    const int w   = hw - h * W_;
    const float* xg = x + (size_t)b * (128 * HW_) + hw;

    // biases: uniform-address scalar loads, hoisted (single SMEM drain here)
    float acc[16];
#pragma unroll
    for (int j = 0; j < 16; ++j) acc[j] = b0[s * 16 + j];
    float bias1[8];
#pragma unroll
    for (int j = 0; j < 8; ++j) bias1[j] = b1[s * 8 + j];
    float bias2[4];
#pragma unroll
    for (int j = 0; j < 4; ++j) bias2[j] = b2[s * 4 + j];
    float bias3[2];
#pragma unroll
    for (int j = 0; j < 2; ++j) bias3[j] = b3[s * 2 + j];
    float bias4 = b4[s];
    float cb0 = cb[0], cb1 = cb[1], cb2 = cb[2];

    __syncthreads();   // weights visible

    // ---- layer 0: 128 -> 64, outputs [s*16, s*16+16)
#pragma unroll 4
    for (int c = 0; c < 128; ++c) {
        float v = xg[(size_t)c * HW_];                     // global, coalesced, L1-shared
        const float4* wr = (const float4*)(S + OFF_W0 + c * 64 + s * 16);
        float4 q0 = wr[0], q1 = wr[1], q2 = wr[2], q3 = wr[3];   // b128 broadcasts
        acc[0]  = fmaf(q0.x, v, acc[0]);  acc[1]  = fmaf(q0.y, v, acc[1]);
        acc[2]  = fmaf(q0.z, v, acc[2]);  acc[3]  = fmaf(q0.w, v, acc[3]);
        acc[4]  = fmaf(q1.x, v, acc[4]);  acc[5]  = fmaf(q1.y, v, acc[5]);
        acc[6]  = fmaf(q1.z, v, acc[6]);  acc[7]  = fmaf(q1.w, v, acc[7]);
        acc[8]  = fmaf(q2.x, v, acc[8]);  acc[9]  = fmaf(q2.y, v, acc[9]);
        acc[10] = fmaf(q2.z, v, acc[10]); acc[11] = fmaf(q2.w, v, acc[11]);
        acc[12] = fmaf(q3.x, v, acc[12]); acc[13] = fmaf(q3.y, v, acc[13]);
        acc[14] = fmaf(q3.z, v, acc[14]); acc[15] = fmaf(q3.w, v, acc[15]);
    }
#pragma unroll
    for (int j = 0; j < 16; ++j) S[L_A0 + p * 65 + s * 16 + j] = eluf(acc[j]);
    __syncthreads();

    // ---- layer 1: 64 -> 32, outputs [s*8, s*8+8)
    float a1[8];
#pragma unroll
    for (int j = 0; j < 8; ++j) a1[j] = bias1[j];
#pragma unroll 8
    for (int c = 0; c < 64; ++c) {
        float v = S[L_A0 + p * 65 + c];
        const float4* wr = (const float4*)(S + OFF_W1 + c * 32 + s * 8);
        float4 q0 = wr[0], q1 = wr[1];
        a1[0] = fmaf(q0.x, v, a1[0]); a1[1] = fmaf(q0.y, v, a1[1]);
        a1[2] = fmaf(q0.z, v, a1[2]); a1[3] = fmaf(q0.w, v, a1[3]);
        a1[4] = fmaf(q1.x, v, a1[4]); a1[5] = fmaf(q1.y, v, a1[5]);
        a1[6] = fmaf(q1.z, v, a1[6]); a1[7] = fmaf(q1.w, v, a1[7]);
    }
#pragma unroll
    for (int j = 0; j < 8; ++j) S[L_A1 + p * 33 + s * 8 + j] = eluf(a1[j]);
    __syncthreads();

    // ---- layer 2: 32 -> 16, outputs [s*4, s*4+4)
    float a2[4];
#pragma unroll
    for (int j = 0; j < 4; ++j) a2[j] = bias2[j];
#pragma unroll 8
    for (int c = 0; c < 32; ++c) {
        float v = S[L_A1 + p * 33 + c];
        float4 q0 = *(const float4*)(S + OFF_W2 + c * 16 + s * 4);
        a2[0] = fmaf(q0.x, v, a2[0]); a2[1] = fmaf(q0.y, v, a2[1]);
        a2[2] = fmaf(q0.z, v, a2[2]); a2[3] = fmaf(q0.w, v, a2[3]);
    }
#pragma unroll
    for (int j = 0; j < 4; ++j) S[L_A2 + p * 17 + s * 4 + j] = eluf(a2[j]);
    __syncthreads();

    // ---- layer 3: 16 -> 8, outputs [s*2, s*2+2)
    float a3[2];
#pragma unroll
    for (int j = 0; j < 2; ++j) a3[j] = bias3[j];
#pragma unroll 8
    for (int c = 0; c < 16; ++c) {
        float v = S[L_A2 + p * 17 + c];
        float2 q0 = *(const float2*)(S + OFF_W3 + c * 8 + s * 2);
        a3[0] = fmaf(q0.x, v, a3[0]); a3[1] = fmaf(q0.y, v, a3[1]);
    }
#pragma unroll
    for (int j = 0; j < 2; ++j) S[L_A3 + p * 9 + s * 2 + j] = eluf(a3[j]);
    __syncthreads();

    // ---- layer 4: 8 -> 4, output s
    {
        float a4 = bias4;
#pragma unroll
        for (int c = 0; c < 8; ++c)
            a4 = fmaf(S[OFF_W4 + c * 4 + s], S[L_A3 + p * 9 + c], a4);
        S[L_A4 + p * 5 + s] = eluf(a4);
    }
    __syncthreads();

    // ---- head 4 -> 3 + plane params (redundant across slices; cheap)
    float v0 = S[L_A4 + p * 5 + 0], v1 = S[L_A4 + p * 5 + 1];
    float v2 = S[L_A4 + p * 5 + 2], v3 = S[L_A4 + p * 5 + 3];
    float y0 = cb0, y1 = cb1, y2 = cb2;
    y0 = fmaf(S[OFF_CW + 0], v0, y0); y1 = fmaf(S[OFF_CW + 1], v0, y1); y2 = fmaf(S[OFF_CW + 2], v0, y2);
    y0 = fmaf(S[OFF_CW + 3], v1, y0); y1 = fmaf(S[OFF_CW + 4], v1, y1); y2 = fmaf(S[OFF_CW + 5], v1, y2);
    y0 = fmaf(S[OFF_CW + 6], v2, y0); y1 = fmaf(S[OFF_CW + 7], v2, y1); y2 = fmaf(S[OFF_CW + 8], v2, y2);
    y0 = fmaf(S[OFF_CW + 9], v3, y0); y1 = fmaf(S[OFF_CW + 10], v3, y1); y2 = fmaf(S[OFF_CW + 11], v3, y2);

    float theta = 0.5235987756f * fast_sigmoid(y0);   // pi/6
    float phi   = 6.2831853072f * fast_sigmoid(y1);   // 2*pi
    float dist  = 83.0f         * fast_sigmoid(y2);
    float st = __sinf(theta), ct = __cosf(theta);
    float sp = __sinf(phi),   cp = __cosf(phi);
    float n1 = st * cp, n2 = st * sp, n3 = ct;
    float inv = __frsqrt_rn(fmaf(n1, n1, fmaf(n2, n2, n3 * n3)));
    n1 *= inv; n2 *= inv; n3 *= inv;

    // ---- 8x8 depth expansion: this slice writes rows 2s and 2s+1
    const float ksc = 1.0f / (8.0f * 715.0f);
    float nu[8];
#pragma unroll
    for (int j = 0; j < 8; ++j) nu[j] = n1 * (((float)j - 3.5f) * ksc);
    const int obase = b * OHW_ + (h * 8) * OW_ + w * 8;
#pragma unroll
    for (int r = 0; r < 2; ++r) {
        int i = s * 2 + r;
        float base = fmaf(n2, ((float)i - 3.5f) * ksc, n3);
        float4 r0, r1;
        r0.x = dist * __builtin_amdgcn_rcpf(base + nu[0]);
        r0.y = dist * __builtin_amdgcn_rcpf(base + nu[1]);
        r0.z = dist * __builtin_amdgcn_rcpf(base + nu[2]);
        r0.w = dist * __builtin_amdgcn_rcpf(base + nu[3]);
        r1.x = dist * __builtin_amdgcn_rcpf(base + nu[4]);
        r1.y = dist * __builtin_amdgcn_rcpf(base + nu[5]);
        r1.z = dist * __builtin_amdgcn_rcpf(base + nu[6]);
        r1.w = dist * __builtin_amdgcn_rcpf(base + nu[7]);
        float4* op = (float4*)(out + obase + i * OW_);
        op[0] = r0;
        op[1] = r1;
    }
}

extern "C" void kernel_launch(void* const* d_in, const int* in_sizes, int n_in,
                              void* d_out, int out_size, void* d_ws, size_t ws_size,
                              hipStream_t stream) {
    const float* x  = (const float*)d_in[0];
    const float* w0 = (const float*)d_in[1];
    const float* b0 = (const float*)d_in[2];
    const float* w1 = (const float*)d_in[3];
    const float* b1 = (const float*)d_in[4];
    const float* w2 = (const float*)d_in[5];
    const float* b2 = (const float*)d_in[6];
    const float* w3 = (const float*)d_in[7];
    const float* b3 = (const float*)d_in[8];
    const float* w4 = (const float*)d_in[9];
    const float* b4 = (const float*)d_in[10];
    const float* cw = (const float*)d_in[11];
    const float* cb = (const float*)d_in[12];
    float* ws  = (float*)d_ws;
    float* out = (float*)d_out;

    prep_weights<<<16, 256, 0, stream>>>(w0, w1, w2, w3, w4, cw, ws);
    lpg_fused<<<NPIX / 64, 256, 0, stream>>>(x, ws, b0, b1, b2, b3, b4, cb, out);
}

// Round 5
// 59.751 us; speedup vs baseline: 2.6493x; 1.5095x over previous
//
#include <hip/hip_runtime.h>
#include <math.h>

#define HW_   6688      // 44*152
#define W_    152
#define NPIX  107008    // 16*44*152
#define OW_   1216      // 152*8
#define OHW_  428032    // 352*1216

typedef _Float16 f16;
typedef _Float16 f16x8 __attribute__((ext_vector_type(8)));
typedef float    f32x4 __attribute__((ext_vector_type(4)));

// LDS float offsets
#define R0    0       // 64 x 68 f32: a0T (stride 68); later a2T/a4T (stride 36)
#define R0S   68
#define R1    4352    // 64 x 36 f32: a1T (stride 36); later a3T
#define R1S   36
#define LY    6656    // 64 x 4 f32: y per pixel
#define LDSF  6912    // 27648 B

#define MFMA(a,b,c) __builtin_amdgcn_mfma_f32_16x16x32_f16((a),(b),(c),0,0,0)

__device__ __forceinline__ float fast_sigmoid(float v) {
    return __builtin_amdgcn_rcpf(1.0f + __expf(-v));
}
__device__ __forceinline__ float eluf(float v) {
    return v > 0.0f ? v : (__expf(v) - 1.0f);
}
// split fp32 -> fp16 hi + fp16 lo (w ~= hi + lo, residual ~2^-22 rel)
__device__ __forceinline__ void split8(const float* v, f16x8& hi, f16x8& lo) {
#pragma unroll
    for (int e = 0; e < 8; ++e) {
        f16 h = (f16)v[e];
        hi[e] = h;
        lo[e] = (f16)(v[e] - (float)h);
    }
}
// 3-term split-precision MFMA: (ah+al)*(bh+bl) ~= ah*bh + ah*bl + al*bh
__device__ __forceinline__ f32x4 mfma3(f16x8 ah, f16x8 al, f16x8 bh, f16x8 bl, f32x4 c) {
    c = MFMA(ah, bh, c);
    c = MFMA(ah, bl, c);
    c = MFMA(al, bh, c);
    return c;
}
__device__ __forceinline__ f32x4 elu4(f32x4 a) {
    f32x4 r;
    r[0] = eluf(a[0]); r[1] = eluf(a[1]); r[2] = eluf(a[2]); r[3] = eluf(a[3]);
    return r;
}

// Block = 256 threads = 4 waves, 64 pixels. All 6 dense layers are 16x16x32
// f16 MFMAs (small layers zero-padded). Weight fragments built once per block
// into VGPRs (weight-stationary). Activations fp32 in LDS between layers.
__global__ __launch_bounds__(256)
void lpg_mfma(const float* __restrict__ x,
              const float* __restrict__ w0, const float* __restrict__ b0,
              const float* __restrict__ w1, const float* __restrict__ b1,
              const float* __restrict__ w2, const float* __restrict__ b2,
              const float* __restrict__ w3, const float* __restrict__ b3,
              const float* __restrict__ w4, const float* __restrict__ b4,
              const float* __restrict__ cw, const float* __restrict__ cb,
              float* __restrict__ out) {
    __shared__ __align__(16) float S[LDSF];

    const int tid  = threadIdx.x;
    const int wv   = __builtin_amdgcn_readfirstlane(tid >> 6);  // wave id
    const int lane = tid & 63;
    const int p    = lane & 15;   // A-row / B-col / C-col index
    const int q    = lane >> 4;   // k-group; C-row group
    const int pixbase = blockIdx.x * 64;

    const float cb0v = cb[0], cb1v = cb[1], cb2v = cb[2];

    // ================= build weight fragments (once per block) =================
    // A-frag convention: row = p, k = kt*32 + 8*q + e  (k-order is arbitrary but
    // MUST match the B-frag k-order — sum over k is permutation-invariant).
    f16x8 w0h[4], w0l[4];               // layer0: wave wv owns out rows [wv*16, +16)
    {
        const float* base = w0 + (wv * 16 + p) * 128 + q * 8;
#pragma unroll
        for (int kt = 0; kt < 4; ++kt) {
            float v[8];
#pragma unroll
            for (int e = 0; e < 8; ++e) v[e] = base[kt * 32 + e];
            split8(v, w0h[kt], w0l[kt]);
        }
    }
    f16x8 w1h[2][2], w1l[2][2];         // layer1: 32x64, both M-tiles per wave
#pragma unroll
    for (int Mt = 0; Mt < 2; ++Mt)
#pragma unroll
        for (int kt = 0; kt < 2; ++kt) {
            float v[8];
#pragma unroll
            for (int e = 0; e < 8; ++e) v[e] = w1[(Mt * 16 + p) * 64 + kt * 32 + q * 8 + e];
            split8(v, w1h[Mt][kt], w1l[Mt][kt]);
        }
    f16x8 w2h, w2l;                     // layer2: 16x32, exact fit
    {
        float v[8];
#pragma unroll
        for (int e = 0; e < 8; ++e) v[e] = w2[p * 32 + q * 8 + e];
        split8(v, w2h, w2l);
    }
    f16x8 w3h, w3l;                     // layer3: 8x16, pad M,K with zeros
    {
        float v[8];
        bool ok = (p < 8) && (q < 2);
#pragma unroll
        for (int e = 0; e < 8; ++e) v[e] = ok ? w3[p * 16 + q * 8 + e] : 0.0f;
        split8(v, w3h, w3l);
    }
    f16x8 w4h, w4l;                     // layer4: 4x8
    {
        float v[8];
        bool ok = (p < 4) && (q == 0);
#pragma unroll
        for (int e = 0; e < 8; ++e) v[e] = ok ? w4[p * 8 + e] : 0.0f;
        split8(v, w4h, w4l);
    }
    f16x8 whh, whl;                     // head: 3x4
    {
        float v[8];
        bool ok = (p < 3) && (q == 0);
#pragma unroll
        for (int e = 0; e < 8; ++e) v[e] = (ok && e < 4) ? cw[p * 4 + e] : 0.0f;
        split8(v, whh, whl);
    }

    // ================= layer 0: 128 -> 64 over 4 pixel-tiles =================
    // wave wv computes out-slice [wv*16,+16) for all 4 tiles; x read from global.
#pragma unroll 2
    for (int t = 0; t < 4; ++t) {
        int pix = pixbase + t * 16 + p;
        int bb  = pix / HW_;
        int hw  = pix - bb * HW_;
        const float* xp = x + (size_t)(bb * 128 + q * 8) * HW_ + hw;
        f16x8 xh[4], xl[4];
#pragma unroll
        for (int kt = 0; kt < 4; ++kt) {
            float v[8];
#pragma unroll
            for (int e = 0; e < 8; ++e) v[e] = xp[(size_t)(kt * 32 + e) * HW_];
            split8(v, xh[kt], xl[kt]);
        }
        f32x4 acc = *(const f32x4*)(b0 + wv * 16 + 4 * q);
#pragma unroll
        for (int kt = 0; kt < 4; ++kt)
            acc = mfma3(w0h[kt], w0l[kt], xh[kt], xl[kt], acc);
        *(f32x4*)(&S[R0 + (t * 16 + p) * R0S + wv * 16 + 4 * q]) = elu4(acc);
    }
    __syncthreads();

    // ============ phase C: wave wv owns pixel rows [wv*16, +16) ============
    const int prow = wv * 16 + p;
    const f32x4 z4 = {0.f, 0.f, 0.f, 0.f};

    // ---- layer 1: 64 -> 32
    f32x4 acc1[2];
    acc1[0] = *(const f32x4*)(b1 + 0  + 4 * q);
    acc1[1] = *(const f32x4*)(b1 + 16 + 4 * q);
#pragma unroll
    for (int kt = 0; kt < 2; ++kt) {
        const float* src = &S[R0 + prow * R0S + kt * 32 + 8 * q];
        float v[8];
#pragma unroll
        for (int e = 0; e < 8; ++e) v[e] = src[e];
        f16x8 bh, bl; split8(v, bh, bl);
        acc1[0] = mfma3(w1h[0][kt], w1l[0][kt], bh, bl, acc1[0]);
        acc1[1] = mfma3(w1h[1][kt], w1l[1][kt], bh, bl, acc1[1]);
    }
#pragma unroll
    for (int Mt = 0; Mt < 2; ++Mt)
        *(f32x4*)(&S[R1 + prow * R1S + Mt * 16 + 4 * q]) = elu4(acc1[Mt]);
    __syncthreads();   // a0T consumed; R0 free for a2T

    // ---- layer 2: 32 -> 16 (writes a2T @R0, stride 36; zero cols 16..31)
    {
        const float* src = &S[R1 + prow * R1S + 8 * q];
        float v[8];
#pragma unroll
        for (int e = 0; e < 8; ++e) v[e] = src[e];
        f16x8 bh, bl; split8(v, bh, bl);
        f32x4 acc = *(const f32x4*)(b2 + 4 * q);
        acc = mfma3(w2h, w2l, bh, bl, acc);
        *(f32x4*)(&S[R0 + prow * R1S + 4 * q]) = elu4(acc);
        *(f32x4*)(&S[R0 + prow * R1S + 16 + 4 * q]) = z4;
    }
    __syncthreads();   // a1T consumed; R1 free for a3T

    // ---- layer 3: 8 -> 16-padded (reads a2T cols 0..31; writes a3T @R1)
    {
        const float* src = &S[R0 + prow * R1S + 8 * q];
        float v[8];
#pragma unroll
        for (int e = 0; e < 8; ++e) v[e] = src[e];
        f16x8 bh, bl; split8(v, bh, bl);
        f32x4 acc = (q < 2) ? *(const f32x4*)(b3 + 4 * q) : z4;
        acc = mfma3(w3h, w3l, bh, bl, acc);
        if (q < 2) *(f32x4*)(&S[R1 + prow * R1S + 4 * q]) = elu4(acc);
        *(f32x4*)(&S[R1 + prow * R1S + 8 + 4 * q]) = z4;            // cols 8..23
        if (q < 2) *(f32x4*)(&S[R1 + prow * R1S + 24 + 4 * q]) = z4; // cols 24..31
    }
    __syncthreads();

    // ---- layer 4: 4 <- 8 (reads a3T; writes a4T @R0)
    {
        const float* src = &S[R1 + prow * R1S + 8 * q];
        float v[8];
#pragma unroll
        for (int e = 0; e < 8; ++e) v[e] = src[e];
        f16x8 bh, bl; split8(v, bh, bl);
        f32x4 acc = (q == 0) ? *(const f32x4*)(b4) : z4;
        acc = mfma3(w4h, w4l, bh, bl, acc);
        if (q == 0) *(f32x4*)(&S[R0 + prow * R1S]) = elu4(acc);
        *(f32x4*)(&S[R0 + prow * R1S + 4 + 4 * q]) = z4;             // cols 4..19
        if (q < 3) *(f32x4*)(&S[R0 + prow * R1S + 20 + 4 * q]) = z4; // cols 20..31
    }
    __syncthreads();

    // ---- head: 3 <- 4 (reads a4T; y lands in q==0 lanes, regs 0..2)
    {
        const float* src = &S[R0 + prow * R1S + 8 * q];
        float v[8];
#pragma unroll
        for (int e = 0; e < 8; ++e) v[e] = src[e];
        f16x8 bh, bl; split8(v, bh, bl);
        f32x4 acc = z4;
        if (q == 0) { acc[0] = cb0v; acc[1] = cb1v; acc[2] = cb2v; }
        acc = mfma3(whh, whl, bh, bl, acc);
        if (q == 0) *(f32x4*)(&S[LY + prow * 4]) = acc;
    }
    __syncthreads();

    // ================= depth expansion (per wave, its 16 pixels) =================
    float y0 = S[LY + prow * 4 + 0];
    float y1 = S[LY + prow * 4 + 1];
    float y2 = S[LY + prow * 4 + 2];

    float theta = 0.5235987756f * fast_sigmoid(y0);   // pi/6
    float phi   = 6.2831853072f * fast_sigmoid(y1);   // 2*pi
    float dist  = 83.0f         * fast_sigmoid(y2);
    float st = __sinf(theta), ct = __cosf(theta);
    float sp = __sinf(phi),   cp = __cosf(phi);
    float n1 = st * cp, n2 = st * sp, n3 = ct;
    float inv = __frsqrt_rn(fmaf(n1, n1, fmaf(n2, n2, n3 * n3)));
    n1 *= inv; n2 *= inv; n3 *= inv;

    const float ksc = 1.0f / (8.0f * 715.0f);
    float nu[8];
#pragma unroll
    for (int j = 0; j < 8; ++j) nu[j] = n1 * (((float)j - 3.5f) * ksc);

    int pix = pixbase + prow;
    int bb  = pix / HW_;
    int hw  = pix - bb * HW_;
    int hh  = hw / W_;
    int ww  = hw - hh * W_;
    const int obase = bb * OHW_ + (hh * 8) * OW_ + ww * 8;
#pragma unroll
    for (int r = 0; r < 2; ++r) {
        int i = q * 2 + r;                           // this lane writes rows 2q, 2q+1
        float base = fmaf(n2, ((float)i - 3.5f) * ksc, n3);
        float4 r0, r1;
        r0.x = dist * __builtin_amdgcn_rcpf(base + nu[0]);
        r0.y = dist * __builtin_amdgcn_rcpf(base + nu[1]);
        r0.z = dist * __builtin_amdgcn_rcpf(base + nu[2]);
        r0.w = dist * __builtin_amdgcn_rcpf(base + nu[3]);
        r1.x = dist * __builtin_amdgcn_rcpf(base + nu[4]);
        r1.y = dist * __builtin_amdgcn_rcpf(base + nu[5]);
        r1.z = dist * __builtin_amdgcn_rcpf(base + nu[6]);
        r1.w = dist * __builtin_amdgcn_rcpf(base + nu[7]);
        float4* op = (float4*)(out + obase + i * OW_);
        op[0] = r0;
        op[1] = r1;
    }
}

extern "C" void kernel_launch(void* const* d_in, const int* in_sizes, int n_in,
                              void* d_out, int out_size, void* d_ws, size_t ws_size,
                              hipStream_t stream) {
    const float* x  = (const float*)d_in[0];
    const float* w0 = (const float*)d_in[1];
    const float* b0 = (const float*)d_in[2];
    const float* w1 = (const float*)d_in[3];
    const float* b1 = (const float*)d_in[4];
    const float* w2 = (const float*)d_in[5];
    const float* b2 = (const float*)d_in[6];
    const float* w3 = (const float*)d_in[7];
    const float* b3 = (const float*)d_in[8];
    const float* w4 = (const float*)d_in[9];
    const float* b4 = (const float*)d_in[10];
    const float* cw = (const float*)d_in[11];
    const float* cb = (const float*)d_in[12];
    float* outp = (float*)d_out;

    lpg_mfma<<<NPIX / 64, 256, 0, stream>>>(x, w0, b0, w1, b1, w2, b2, w3, b3,
                                            w4, b4, cw, cb, outp);
}

// Round 8
// 34.048 us; speedup vs baseline: 4.6493x; 1.7549x over previous
//
#include <hip/hip_runtime.h>
#include <math.h>

#define HW_   6688      // 44*152
#define W_    152
#define NPIX  107008    // 16*44*152
#define OW_   1216      // 152*8
#define OHW_  428032    // 352*1216

typedef _Float16 f16;
typedef _Float16 f16x2 __attribute__((ext_vector_type(2)));
typedef _Float16 f16x4 __attribute__((ext_vector_type(4)));
typedef _Float16 f16x8 __attribute__((ext_vector_type(8)));
typedef float    f32x4 __attribute__((ext_vector_type(4)));

#define MFMA(a,b,c) __builtin_amdgcn_mfma_f32_16x16x32_f16((a),(b),(c),0,0,0)

// LDS layout (f16-element offsets). Strides are multiples of 8 f16 (16B) so
// b128 accesses stay aligned. a1/a2/a3 overlay the dead x region after L0.
#define SX_STR   136            // x  [128][136] f16 -> 34816 B
#define SA1_STR  40             // a1 [128][40]  f16 -> ends 5115
#define SA2_OFF  5120           // a2 [128][24]  f16
#define SA2_STR  24             //   -> ends 8183
#define SA3_OFF  8192           // a3 [128][16]  f16
#define SA3_STR  16             //   -> ends 10239  (< 17408 = x region)
#define SA0_OFFB 34816          // a0 [128][72]  f16 (byte offset)
#define SA0_STR  72             //   -> ends 34816+18432 = 53248
#define LDSB     53248          // 52 KB -> 3 blocks/CU

__device__ __forceinline__ float fast_sigmoid(float v) {
    return __builtin_amdgcn_rcpf(1.0f + __expf(-v));
}
__device__ __forceinline__ float eluf(float v) {
    return v > 0.0f ? v : (__expf(v) - 1.0f);
}
// split fp32 -> fp16 hi + fp16 lo (w ~= hi + lo)
__device__ __forceinline__ void split8(const float* v, f16x8& hi, f16x8& lo) {
#pragma unroll
    for (int e = 0; e < 8; ++e) {
        f16 h = (f16)v[e];
        hi[e] = h;
        lo[e] = (f16)(v[e] - (float)h);
    }
}
__device__ __forceinline__ f16x4 elu_cvt4(f32x4 a) {
    f16x4 r;
    r[0] = (f16)eluf(a[0]); r[1] = (f16)eluf(a[1]);
    r[2] = (f16)eluf(a[2]); r[3] = (f16)eluf(a[3]);
    return r;
}

// 256 threads = 4 waves, 128 pixels/block. x staged once to LDS as f16;
// all dense layers = 16x16x32 f16 MFMA with split (hi+lo) weights in VGPRs.
// Cross-lane LDS handoffs between layers are fenced with __syncthreads()
// (the per-thread memory model lets the compiler reorder ds_read above a
// non-aliasing ds_write — wave-lockstep alone is NOT sufficient).
__global__ __launch_bounds__(256)
void lpg_mfma(const float* __restrict__ x,
              const float* __restrict__ w0, const float* __restrict__ b0,
              const float* __restrict__ w1, const float* __restrict__ b1,
              const float* __restrict__ w2, const float* __restrict__ b2,
              const float* __restrict__ w3, const float* __restrict__ b3,
              const float* __restrict__ w4, const float* __restrict__ b4,
              const float* __restrict__ cw, const float* __restrict__ cb,
              float* __restrict__ out) {
    __shared__ __align__(16) unsigned char S[LDSB];
    f16* SX  = (f16*)S;                    // x; later a1/a2/a3 overlays
    f16* SA0 = (f16*)(S + SA0_OFFB);

    const int tid  = threadIdx.x;
    const int wv   = __builtin_amdgcn_readfirstlane(tid >> 6);
    const int lane = tid & 63;
    const int p    = lane & 15;   // MFMA row/col index
    const int q    = lane >> 4;   // k-group / C-row group
    const int pixbase = blockIdx.x * 128;

    // ---- stage x -> LDS f16 [pix][ch]: thread (i = tid&127) loads 64 channels
    {
        const int i     = tid & 127;
        const int chalf = (tid >> 7) * 64;
        int pix = pixbase + i;
        int bb  = pix / HW_;
        int hw  = pix - bb * HW_;
        const float* xp = x + ((size_t)bb * 128 + chalf) * HW_ + hw;
        f16* dst = SX + i * SX_STR + chalf;
#pragma unroll 8
        for (int k = 0; k < 32; ++k) {
            float v0 = xp[(size_t)(2 * k) * HW_];
            float v1 = xp[(size_t)(2 * k + 1) * HW_];
            f16x2 h; h[0] = (f16)v0; h[1] = (f16)v1;
            *(f16x2*)(dst + 2 * k) = h;
        }
    }

    // ---- weight fragments (global loads overlap the staging latency) ----
    f16x8 w0h[4], w0l[4];                   // wave's 16 out-ch slice of w0
    {
        const float* wr = w0 + (wv * 16 + p) * 128 + q * 8;
#pragma unroll
        for (int kt = 0; kt < 4; ++kt) {
            float v[8];
#pragma unroll
            for (int e = 0; e < 8; ++e) v[e] = wr[kt * 32 + e];
            split8(v, w0h[kt], w0l[kt]);
        }
    }
    f16x8 w1h[2][2], w1l[2][2];
#pragma unroll
    for (int Mt = 0; Mt < 2; ++Mt)
#pragma unroll
        for (int kt = 0; kt < 2; ++kt) {
            float v[8];
#pragma unroll
            for (int e = 0; e < 8; ++e) v[e] = w1[(Mt * 16 + p) * 64 + kt * 32 + q * 8 + e];
            split8(v, w1h[Mt][kt], w1l[Mt][kt]);
        }
    f16x8 w2h, w2l;
    {
        float v[8];
#pragma unroll
        for (int e = 0; e < 8; ++e) v[e] = w2[p * 32 + q * 8 + e];
        split8(v, w2h, w2l);
    }
    f16x8 w3h, w3l;
    {
        float v[8];
        bool ok = (p < 8) && (q < 2);
#pragma unroll
        for (int e = 0; e < 8; ++e) v[e] = ok ? w3[p * 16 + q * 8 + e] : 0.0f;
        split8(v, w3h, w3l);
    }
    f16x8 w4h, w4l;
    {
        float v[8];
        bool ok = (p < 4) && (q == 0);
#pragma unroll
        for (int e = 0; e < 8; ++e) v[e] = ok ? w4[p * 8 + e] : 0.0f;
        split8(v, w4h, w4l);
    }
    f16x8 whh, whl;
    {
        float v[8];
        bool ok = (p < 3) && (q == 0);
#pragma unroll
        for (int e = 0; e < 8; ++e) v[e] = (ok && e < 4) ? cw[p * 4 + e] : 0.0f;
        split8(v, whh, whl);
    }

    // biases (hoisted)
    const f32x4 z4 = {0.f, 0.f, 0.f, 0.f};
    f32x4 b0v  = *(const f32x4*)(b0 + wv * 16 + 4 * q);
    f32x4 b1v0 = *(const f32x4*)(b1 + 4 * q);
    f32x4 b1v1 = *(const f32x4*)(b1 + 16 + 4 * q);
    f32x4 b2v  = *(const f32x4*)(b2 + 4 * q);
    f32x4 b3v  = *(const f32x4*)(b3 + (q & 1) * 4);
    f32x4 b4v  = *(const f32x4*)(b4);
    float cb0v = cb[0], cb1v = cb[1], cb2v = cb[2];

    __syncthreads();   // (1) x staged

    // ---- layer 0: 128 -> 64. Wave computes its 16-ch slice for all 8 tiles.
#pragma unroll 2
    for (int t = 0; t < 8; ++t) {
        const f16* bp = SX + (t * 16 + p) * SX_STR + q * 8;
        f32x4 acc = b0v;
#pragma unroll
        for (int kt = 0; kt < 4; ++kt) {
            f16x8 bf = *(const f16x8*)(bp + kt * 32);
            acc = MFMA(w0h[kt], bf, acc);
            acc = MFMA(w0l[kt], bf, acc);
        }
        *(f16x4*)(SA0 + (t * 16 + p) * SA0_STR + wv * 16 + 4 * q) = elu_cvt4(acc);
    }
    __syncthreads();   // (2) a0 complete; x region dead -> reused below

    // ---- phase C: wave owns pixels [wv*32, wv*32+32); 2 tiles per layer ----
    const int i0a = wv * 32 + p;        // tile nt=0
    const int i0b = wv * 32 + 16 + p;   // tile nt=1

    // layer 1: 64 -> 32
    {
        f32x4 cA0 = b1v0, cA1 = b1v1, cB0 = b1v0, cB1 = b1v1;
#pragma unroll
        for (int kt = 0; kt < 2; ++kt) {
            f16x8 bfA = *(const f16x8*)(SA0 + i0a * SA0_STR + kt * 32 + q * 8);
            f16x8 bfB = *(const f16x8*)(SA0 + i0b * SA0_STR + kt * 32 + q * 8);
            cA0 = MFMA(w1h[0][kt], bfA, cA0); cA0 = MFMA(w1l[0][kt], bfA, cA0);
            cA1 = MFMA(w1h[1][kt], bfA, cA1); cA1 = MFMA(w1l[1][kt], bfA, cA1);
            cB0 = MFMA(w1h[0][kt], bfB, cB0); cB0 = MFMA(w1l[0][kt], bfB, cB0);
            cB1 = MFMA(w1h[1][kt], bfB, cB1); cB1 = MFMA(w1l[1][kt], bfB, cB1);
        }
        *(f16x4*)(SX + i0a * SA1_STR + 4 * q)      = elu_cvt4(cA0);
        *(f16x4*)(SX + i0a * SA1_STR + 16 + 4 * q) = elu_cvt4(cA1);
        *(f16x4*)(SX + i0b * SA1_STR + 4 * q)      = elu_cvt4(cB0);
        *(f16x4*)(SX + i0b * SA1_STR + 16 + 4 * q) = elu_cvt4(cB1);
    }
    __syncthreads();   // (3) a1 handoff (cross-lane)

    // layer 2: 32 -> 16
    {
        f16x8 bfA = *(const f16x8*)(SX + i0a * SA1_STR + q * 8);
        f16x8 bfB = *(const f16x8*)(SX + i0b * SA1_STR + q * 8);
        f32x4 cA = b2v, cB = b2v;
        cA = MFMA(w2h, bfA, cA); cA = MFMA(w2l, bfA, cA);
        cB = MFMA(w2h, bfB, cB); cB = MFMA(w2l, bfB, cB);
        *(f16x4*)(SX + SA2_OFF + i0a * SA2_STR + 4 * q) = elu_cvt4(cA);
        *(f16x4*)(SX + SA2_OFF + i0b * SA2_STR + 4 * q) = elu_cvt4(cB);
    }
    __syncthreads();   // (4) a2 handoff

    // layer 3: 16 -> 8 (K valid for q<2)
    {
        f16x8 bfA = *(const f16x8*)(SX + SA2_OFF + i0a * SA2_STR + (q & 1) * 8);
        f16x8 bfB = *(const f16x8*)(SX + SA2_OFF + i0b * SA2_STR + (q & 1) * 8);
        if (q >= 2) { bfA = (f16x8){}; bfB = (f16x8){}; }
        f32x4 cA = (q < 2) ? b3v : z4, cB = (q < 2) ? b3v : z4;
        cA = MFMA(w3h, bfA, cA); cA = MFMA(w3l, bfA, cA);
        cB = MFMA(w3h, bfB, cB); cB = MFMA(w3l, bfB, cB);
        if (q < 2) {
            *(f16x4*)(SX + SA3_OFF + i0a * SA3_STR + 4 * q) = elu_cvt4(cA);
            *(f16x4*)(SX + SA3_OFF + i0b * SA3_STR + 4 * q) = elu_cvt4(cB);
        }
    }
    __syncthreads();   // (5) a3 handoff

    // layer 4 (8->4) + head (4->3): a4 stays in registers (same-lane use)
    f32x4 cyA, cyB;
    {
        f16x8 bfA = *(const f16x8*)(SX + SA3_OFF + i0a * SA3_STR);
        f16x8 bfB = *(const f16x8*)(SX + SA3_OFF + i0b * SA3_STR);
        if (q != 0) { bfA = (f16x8){}; bfB = (f16x8){}; }
        f32x4 cA = (q == 0) ? b4v : z4, cB = (q == 0) ? b4v : z4;
        cA = MFMA(w4h, bfA, cA); cA = MFMA(w4l, bfA, cA);
        cB = MFMA(w4h, bfB, cB); cB = MFMA(w4l, bfB, cB);

        f16x8 hA = (f16x8){}, hB = (f16x8){};
        if (q == 0) {
#pragma unroll
            for (int e = 0; e < 4; ++e) {
                hA[e] = (f16)eluf(cA[e]);
                hB[e] = (f16)eluf(cB[e]);
            }
        }
        cyA = z4; cyB = z4;
        if (q == 0) {
            cyA[0] = cb0v; cyA[1] = cb1v; cyA[2] = cb2v;
            cyB[0] = cb0v; cyB[1] = cb1v; cyB[2] = cb2v;
        }
        cyA = MFMA(whh, hA, cyA); cyA = MFMA(whl, hA, cyA);
        cyB = MFMA(whh, hB, cyB); cyB = MFMA(whl, hB, cyB);
    }

    // ---- epilogue: y via shuffle from the q==0 lane of column p ----
#pragma unroll
    for (int nt = 0; nt < 2; ++nt) {
        const int i0 = wv * 32 + nt * 16 + p;
        float y0 = __shfl(nt ? cyB[0] : cyA[0], p);
        float y1 = __shfl(nt ? cyB[1] : cyA[1], p);
        float y2 = __shfl(nt ? cyB[2] : cyA[2], p);

        float theta = 0.5235987756f * fast_sigmoid(y0);   // pi/6
        float phi   = 6.2831853072f * fast_sigmoid(y1);   // 2*pi
        float dist  = 83.0f         * fast_sigmoid(y2);
        float st = __sinf(theta), ct = __cosf(theta);
        float sp = __sinf(phi),   cp = __cosf(phi);
        float n1 = st * cp, n2 = st * sp, n3 = ct;
        float inv = __frsqrt_rn(fmaf(n1, n1, fmaf(n2, n2, n3 * n3)));
        n1 *= inv; n2 *= inv; n3 *= inv;

        const float ksc = 1.0f / (8.0f * 715.0f);
        float nu[8];
#pragma unroll
        for (int j = 0; j < 8; ++j) nu[j] = n1 * (((float)j - 3.5f) * ksc);

        int pix = pixbase + i0;
        int bb  = pix / HW_;
        int hw  = pix - bb * HW_;
        int hh  = hw / W_;
        int ww  = hw - hh * W_;
        const int obase = bb * OHW_ + (hh * 8) * OW_ + ww * 8;
#pragma unroll
        for (int r = 0; r < 2; ++r) {
            int i = q * 2 + r;                     // lane (p,q) writes rows 2q,2q+1
            float base = fmaf(n2, ((float)i - 3.5f) * ksc, n3);
            float4 r0, r1;
            r0.x = dist * __builtin_amdgcn_rcpf(base + nu[0]);
            r0.y = dist * __builtin_amdgcn_rcpf(base + nu[1]);
            r0.z = dist * __builtin_amdgcn_rcpf(base + nu[2]);
            r0.w = dist * __builtin_amdgcn_rcpf(base + nu[3]);
            r1.x = dist * __builtin_amdgcn_rcpf(base + nu[4]);
            r1.y = dist * __builtin_amdgcn_rcpf(base + nu[5]);
            r1.z = dist * __builtin_amdgcn_rcpf(base + nu[6]);
            r1.w = dist * __builtin_amdgcn_rcpf(base + nu[7]);
            float4* op = (float4*)(out + obase + i * OW_);
            op[0] = r0;
            op[1] = r1;
        }
    }
}

extern "C" void kernel_launch(void* const* d_in, const int* in_sizes, int n_in,
                              void* d_out, int out_size, void* d_ws, size_t ws_size,
                              hipStream_t stream) {
    const float* x  = (const float*)d_in[0];
    const float* w0 = (const float*)d_in[1];
    const float* b0 = (const float*)d_in[2];
    const float* w1 = (const float*)d_in[3];
    const float* b1 = (const float*)d_in[4];
    const float* w2 = (const float*)d_in[5];
    const float* b2 = (const float*)d_in[6];
    const float* w3 = (const float*)d_in[7];
    const float* b3 = (const float*)d_in[8];
    const float* w4 = (const float*)d_in[9];
    const float* b4 = (const float*)d_in[10];
    const float* cw = (const float*)d_in[11];
    const float* cb = (const float*)d_in[12];
    float* outp = (float*)d_out;

    lpg_mfma<<<NPIX / 128, 256, 0, stream>>>(x, w0, b0, w1, b1, w2, b2, w3, b3,
                                             w4, b4, cw, cb, outp);
}

// Round 10
// 30.914 us; speedup vs baseline: 5.1206x; 1.1014x over previous
//
#include <hip/hip_runtime.h>
#include <math.h>

#define HW_   6688      // 44*152
#define W_    152
#define NPIX  107008    // 16*44*152
#define OW_   1216      // 152*8
#define OHW_  428032    // 352*1216

typedef _Float16 f16;
typedef _Float16 f16x2 __attribute__((ext_vector_type(2)));
typedef _Float16 f16x4 __attribute__((ext_vector_type(4)));
typedef _Float16 f16x8 __attribute__((ext_vector_type(8)));
typedef float    f32x4 __attribute__((ext_vector_type(4)));

#define MFMA(a,b,c) __builtin_amdgcn_mfma_f32_16x16x32_f16((a),(b),(c),0,0,0)

// LDS layout (f16 units). x staged in TWO 64-channel halves into [128][72].
// Phase-C buffers a1/a2/a3 live in DISJOINT regions (cross-wave safety with
// wave-level fences: no address is written in one phase while readable in
// another — r9's a3-over-a1 overlay raced across waves).
#define SXH_STR  72             // x-half [128][72] at 0 -> 9216 f16 (dead after L0)
#define SA1_STR  40             // a1 [128][40] at 0     -> ends 5120
#define SA2_OFF  5120           // a2 [128][24]          -> ends 8192
#define SA2_STR  24
#define SA3_OFF  8192           // a3 [128][16] DEDICATED -> ends 10240
#define SA3_STR  16
#define SA0_OFF  10240          // a0 [128][72]          -> ends 19456
#define SA0_STR  72
#define LDSF16   19456          // 38912 B -> 4 blocks/CU (152 KB)

__device__ __forceinline__ float fast_sigmoid(float v) {
    return __builtin_amdgcn_rcpf(1.0f + __expf(-v));
}
__device__ __forceinline__ float eluf(float v) {
    return v > 0.0f ? v : (__expf(v) - 1.0f);
}
__device__ __forceinline__ void split8(const float* v, f16x8& hi, f16x8& lo) {
#pragma unroll
    for (int e = 0; e < 8; ++e) {
        f16 h = (f16)v[e];
        hi[e] = h;
        lo[e] = (f16)(v[e] - (float)h);
    }
}
__device__ __forceinline__ f16x4 elu_cvt4(f32x4 a) {
    f16x4 r;
    r[0] = (f16)eluf(a[0]); r[1] = (f16)eluf(a[1]);
    r[2] = (f16)eluf(a[2]); r[3] = (f16)eluf(a[3]);
    return r;
}
// Intra-wave LDS handoff fence: the LDS pipe processes a wave's DS ops in
// issue order; sched_barrier(0) pins compile-time order. Cross-wave safety
// comes from disjoint regions, not this fence.
__device__ __forceinline__ void wave_fence() {
    __builtin_amdgcn_sched_barrier(0);
    __builtin_amdgcn_wave_barrier();
    __builtin_amdgcn_sched_barrier(0);
}
// stage 32 channels (stride HW_) of one pixel as f16 into LDS
__device__ __forceinline__ void stage32(const float* __restrict__ xp, f16* dst) {
#pragma unroll 8
    for (int k = 0; k < 32; k += 2) {
        float v0 = xp[(size_t)k * HW_];
        float v1 = xp[(size_t)(k + 1) * HW_];
        f16x2 h; h[0] = (f16)v0; h[1] = (f16)v1;
        *(f16x2*)(dst + k) = h;
    }
}

// 256 threads = 4 waves, 128 pixels/block. x staged in 2 channel-halves
// (38 KB LDS -> 4 blocks/CU = 16 waves/CU). All layers are 16x16x32 f16 MFMA
// with split (hi+lo) weights. After the a0 block-barrier, everything is
// wave-private: LDS handoffs use wave fences, not s_barrier.
__global__ __launch_bounds__(256, 4)
void lpg_mfma(const float* __restrict__ x,
              const float* __restrict__ w0, const float* __restrict__ b0,
              const float* __restrict__ w1, const float* __restrict__ b1,
              const float* __restrict__ w2, const float* __restrict__ b2,
              const float* __restrict__ w3, const float* __restrict__ b3,
              const float* __restrict__ w4, const float* __restrict__ b4,
              const float* __restrict__ cw, const float* __restrict__ cb,
              float* __restrict__ out) {
    __shared__ __align__(16) f16 S[LDSF16];
    f16* SX  = S;                 // x-half; later a1/a2/a3 (disjoint) overlays
    f16* SA0 = S + SA0_OFF;

    const int tid  = threadIdx.x;
    const int wv   = __builtin_amdgcn_readfirstlane(tid >> 6);
    const int lane = tid & 63;
    const int p    = lane & 15;   // MFMA row/col index
    const int q    = lane >> 4;   // k-group / C-row group
    const int pixbase = blockIdx.x * 128;

    // staging addresses: thread (i = tid&127) stages pixel i, 32 channels/half
    const int i    = tid & 127;
    const int csub = (tid >> 7) * 32;          // 0 or 32 within the half
    int pixs = pixbase + i;
    int bbs  = pixs / HW_;
    int hws  = pixs - bbs * HW_;
    const float* xps = x + ((size_t)bbs * 128 + csub) * HW_ + hws;
    f16* dsts = SX + i * SXH_STR + csub;

    // ---- stage half 0 (channels 0..63)
    stage32(xps, dsts);

    // ---- layer-0 weights for k-half 0 + bias; accs for all 8 pixel tiles
    const int w0row = (wv * 16 + p) * 128 + q * 8;
    f16x8 w0h[2], w0l[2];
#pragma unroll
    for (int kt = 0; kt < 2; ++kt) {
        float v[8];
#pragma unroll
        for (int e = 0; e < 8; ++e) v[e] = w0[w0row + kt * 32 + e];
        split8(v, w0h[kt], w0l[kt]);
    }
    f32x4 acc[8];
    {
        f32x4 b0v = *(const f32x4*)(b0 + wv * 16 + 4 * q);
#pragma unroll
        for (int t = 0; t < 8; ++t) acc[t] = b0v;
    }
    __syncthreads();   // (1) half 0 staged

#pragma unroll 2
    for (int t = 0; t < 8; ++t) {
        const f16* bp = SX + (t * 16 + p) * SXH_STR + q * 8;
        f16x8 bf0 = *(const f16x8*)(bp);
        f16x8 bf1 = *(const f16x8*)(bp + 32);
        acc[t] = MFMA(w0h[0], bf0, acc[t]); acc[t] = MFMA(w0l[0], bf0, acc[t]);
        acc[t] = MFMA(w0h[1], bf1, acc[t]); acc[t] = MFMA(w0l[1], bf1, acc[t]);
    }
    __syncthreads();   // (2) all waves done reading half 0

    // ---- stage half 1 (channels 64..127) over the same buffer
    stage32(xps + (size_t)64 * HW_, dsts);
#pragma unroll
    for (int kt = 0; kt < 2; ++kt) {     // w0 k-half 1 (reuses registers)
        float v[8];
#pragma unroll
        for (int e = 0; e < 8; ++e) v[e] = w0[w0row + 64 + kt * 32 + e];
        split8(v, w0h[kt], w0l[kt]);
    }
    __syncthreads();   // (3) half 1 staged

#pragma unroll 2
    for (int t = 0; t < 8; ++t) {
        const f16* bp = SX + (t * 16 + p) * SXH_STR + q * 8;
        f16x8 bf0 = *(const f16x8*)(bp);
        f16x8 bf1 = *(const f16x8*)(bp + 32);
        acc[t] = MFMA(w0h[0], bf0, acc[t]); acc[t] = MFMA(w0l[0], bf0, acc[t]);
        acc[t] = MFMA(w0h[1], bf1, acc[t]); acc[t] = MFMA(w0l[1], bf1, acc[t]);
        *(f16x4*)(SA0 + (t * 16 + p) * SA0_STR + wv * 16 + 4 * q) = elu_cvt4(acc[t]);
    }
    __syncthreads();   // (4) a0 complete — last block barrier

    // ================= phase C: wave-private (fences only) =================
    // weights/biases for layers 1..head (loaded here to bound VGPR pressure)
    f16x8 w1h[2][2], w1l[2][2];
#pragma unroll
    for (int Mt = 0; Mt < 2; ++Mt)
#pragma unroll
        for (int kt = 0; kt < 2; ++kt) {
            float v[8];
#pragma unroll
            for (int e = 0; e < 8; ++e) v[e] = w1[(Mt * 16 + p) * 64 + kt * 32 + q * 8 + e];
            split8(v, w1h[Mt][kt], w1l[Mt][kt]);
        }
    f16x8 w2h, w2l;
    {
        float v[8];
#pragma unroll
        for (int e = 0; e < 8; ++e) v[e] = w2[p * 32 + q * 8 + e];
        split8(v, w2h, w2l);
    }
    f16x8 w3h, w3l;
    {
        float v[8];
        bool ok = (p < 8) && (q < 2);
#pragma unroll
        for (int e = 0; e < 8; ++e) v[e] = ok ? w3[p * 16 + q * 8 + e] : 0.0f;
        split8(v, w3h, w3l);
    }
    f16x8 w4h, w4l;
    {
        float v[8];
        bool ok = (p < 4) && (q == 0);
#pragma unroll
        for (int e = 0; e < 8; ++e) v[e] = ok ? w4[p * 8 + e] : 0.0f;
        split8(v, w4h, w4l);
    }
    f16x8 whh, whl;
    {
        float v[8];
        bool ok = (p < 3) && (q == 0);
#pragma unroll
        for (int e = 0; e < 8; ++e) v[e] = (ok && e < 4) ? cw[p * 4 + e] : 0.0f;
        split8(v, whh, whl);
    }
    const f32x4 z4 = {0.f, 0.f, 0.f, 0.f};
    f32x4 b1v0 = *(const f32x4*)(b1 + 4 * q);
    f32x4 b1v1 = *(const f32x4*)(b1 + 16 + 4 * q);
    f32x4 b2v  = *(const f32x4*)(b2 + 4 * q);
    f32x4 b3v  = *(const f32x4*)(b3 + (q & 1) * 4);
    f32x4 b4v  = *(const f32x4*)(b4);
    float cb0v = cb[0], cb1v = cb[1], cb2v = cb[2];

    const int i0a = wv * 32 + p;        // tile A (nt=0)
    const int i0b = wv * 32 + 16 + p;   // tile B (nt=1)

    // ---- layer 1: 64 -> 32
    {
        f32x4 cA0 = b1v0, cA1 = b1v1, cB0 = b1v0, cB1 = b1v1;
#pragma unroll
        for (int kt = 0; kt < 2; ++kt) {
            f16x8 bfA = *(const f16x8*)(SA0 + i0a * SA0_STR + kt * 32 + q * 8);
            f16x8 bfB = *(const f16x8*)(SA0 + i0b * SA0_STR + kt * 32 + q * 8);
            cA0 = MFMA(w1h[0][kt], bfA, cA0); cA0 = MFMA(w1l[0][kt], bfA, cA0);
            cA1 = MFMA(w1h[1][kt], bfA, cA1); cA1 = MFMA(w1l[1][kt], bfA, cA1);
            cB0 = MFMA(w1h[0][kt], bfB, cB0); cB0 = MFMA(w1l[0][kt], bfB, cB0);
            cB1 = MFMA(w1h[1][kt], bfB, cB1); cB1 = MFMA(w1l[1][kt], bfB, cB1);
        }
        *(f16x4*)(SX + i0a * SA1_STR + 4 * q)      = elu_cvt4(cA0);
        *(f16x4*)(SX + i0a * SA1_STR + 16 + 4 * q) = elu_cvt4(cA1);
        *(f16x4*)(SX + i0b * SA1_STR + 4 * q)      = elu_cvt4(cB0);
        *(f16x4*)(SX + i0b * SA1_STR + 16 + 4 * q) = elu_cvt4(cB1);
    }
    wave_fence();   // a1 handoff (intra-wave cross-lane)

    // ---- layer 2: 32 -> 16
    {
        f16x8 bfA = *(const f16x8*)(SX + i0a * SA1_STR + q * 8);
        f16x8 bfB = *(const f16x8*)(SX + i0b * SA1_STR + q * 8);
        f32x4 cA = b2v, cB = b2v;
        cA = MFMA(w2h, bfA, cA); cA = MFMA(w2l, bfA, cA);
        cB = MFMA(w2h, bfB, cB); cB = MFMA(w2l, bfB, cB);
        *(f16x4*)(SX + SA2_OFF + i0a * SA2_STR + 4 * q) = elu_cvt4(cA);
        *(f16x4*)(SX + SA2_OFF + i0b * SA2_STR + 4 * q) = elu_cvt4(cB);
    }
    wave_fence();   // a2 handoff

    // ---- layer 3: 16 -> 8 (K valid for q<2); a3 in its own region
    {
        f16x8 bfA = *(const f16x8*)(SX + SA2_OFF + i0a * SA2_STR + (q & 1) * 8);
        f16x8 bfB = *(const f16x8*)(SX + SA2_OFF + i0b * SA2_STR + (q & 1) * 8);
        if (q >= 2) { bfA = (f16x8){}; bfB = (f16x8){}; }
        f32x4 cA = (q < 2) ? b3v : z4, cB = (q < 2) ? b3v : z4;
        cA = MFMA(w3h, bfA, cA); cA = MFMA(w3l, bfA, cA);
        cB = MFMA(w3h, bfB, cB); cB = MFMA(w3l, bfB, cB);
        if (q < 2) {
            *(f16x4*)(SX + SA3_OFF + i0a * SA3_STR + 4 * q) = elu_cvt4(cA);
            *(f16x4*)(SX + SA3_OFF + i0b * SA3_STR + 4 * q) = elu_cvt4(cB);
        }
    }
    wave_fence();   // a3 handoff

    // ---- layer 4 (8->4) + head (4->3): a4 stays in registers
    f32x4 cyA, cyB;
    {
        f16x8 bfA = *(const f16x8*)(SX + SA3_OFF + i0a * SA3_STR);
        f16x8 bfB = *(const f16x8*)(SX + SA3_OFF + i0b * SA3_STR);
        if (q != 0) { bfA = (f16x8){}; bfB = (f16x8){}; }
        f32x4 cA = (q == 0) ? b4v : z4, cB = (q == 0) ? b4v : z4;
        cA = MFMA(w4h, bfA, cA); cA = MFMA(w4l, bfA, cA);
        cB = MFMA(w4h, bfB, cB); cB = MFMA(w4l, bfB, cB);

        f16x8 hA = (f16x8){}, hB = (f16x8){};
        if (q == 0) {
#pragma unroll
            for (int e = 0; e < 4; ++e) {
                hA[e] = (f16)eluf(cA[e]);
                hB[e] = (f16)eluf(cB[e]);
            }
        }
        cyA = z4; cyB = z4;
        if (q == 0) {
            cyA[0] = cb0v; cyA[1] = cb1v; cyA[2] = cb2v;
            cyB[0] = cb0v; cyB[1] = cb1v; cyB[2] = cb2v;
        }
        cyA = MFMA(whh, hA, cyA); cyA = MFMA(whl, hA, cyA);
        cyB = MFMA(whh, hB, cyB); cyB = MFMA(whl, hB, cyB);
    }

    // ---- epilogue: y via shuffle from the q==0 lane of column p ----
#pragma unroll
    for (int nt = 0; nt < 2; ++nt) {
        const int i0 = wv * 32 + nt * 16 + p;
        float y0 = __shfl(nt ? cyB[0] : cyA[0], p);
        float y1 = __shfl(nt ? cyB[1] : cyA[1], p);
        float y2 = __shfl(nt ? cyB[2] : cyA[2], p);

        float theta = 0.5235987756f * fast_sigmoid(y0);   // pi/6
        float phi   = 6.2831853072f * fast_sigmoid(y1);   // 2*pi
        float dist  = 83.0f         * fast_sigmoid(y2);
        float st = __sinf(theta), ct = __cosf(theta);
        float sp = __sinf(phi),   cp = __cosf(phi);
        float n1 = st * cp, n2 = st * sp, n3 = ct;
        float inv = __frsqrt_rn(fmaf(n1, n1, fmaf(n2, n2, n3 * n3)));
        n1 *= inv; n2 *= inv; n3 *= inv;

        const float ksc = 1.0f / (8.0f * 715.0f);
        float nu[8];
#pragma unroll
        for (int j = 0; j < 8; ++j) nu[j] = n1 * (((float)j - 3.5f) * ksc);

        int pix = pixbase + i0;
        int bb  = pix / HW_;
        int hw  = pix - bb * HW_;
        int hh  = hw / W_;
        int ww  = hw - hh * W_;
        const int obase = bb * OHW_ + (hh * 8) * OW_ + ww * 8;
#pragma unroll
        for (int r = 0; r < 2; ++r) {
            int irow = q * 2 + r;               // lane (p,q) writes rows 2q,2q+1
            float base = fmaf(n2, ((float)irow - 3.5f) * ksc, n3);
            float4 r0, r1;
            r0.x = dist * __builtin_amdgcn_rcpf(base + nu[0]);
            r0.y = dist * __builtin_amdgcn_rcpf(base + nu[1]);
            r0.z = dist * __builtin_amdgcn_rcpf(base + nu[2]);
            r0.w = dist * __builtin_amdgcn_rcpf(base + nu[3]);
            r1.x = dist * __builtin_amdgcn_rcpf(base + nu[4]);
            r1.y = dist * __builtin_amdgcn_rcpf(base + nu[5]);
            r1.z = dist * __builtin_amdgcn_rcpf(base + nu[6]);
            r1.w = dist * __builtin_amdgcn_rcpf(base + nu[7]);
            float4* op = (float4*)(out + obase + irow * OW_);
            op[0] = r0;
            op[1] = r1;
        }
    }
}

extern "C" void kernel_launch(void* const* d_in, const int* in_sizes, int n_in,
                              void* d_out, int out_size, void* d_ws, size_t ws_size,
                              hipStream_t stream) {
    const float* x  = (const float*)d_in[0];
    const float* w0 = (const float*)d_in[1];
    const float* b0 = (const float*)d_in[2];
    const float* w1 = (const float*)d_in[3];
    const float* b1 = (const float*)d_in[4];
    const float* w2 = (const float*)d_in[5];
    const float* b2 = (const float*)d_in[6];
    const float* w3 = (const float*)d_in[7];
    const float* b3 = (const float*)d_in[8];
    const float* w4 = (const float*)d_in[9];
    const float* b4 = (const float*)d_in[10];
    const float* cw = (const float*)d_in[11];
    const float* cb = (const float*)d_in[12];
    float* outp = (float*)d_out;

    lpg_mfma<<<NPIX / 128, 256, 0, stream>>>(x, w0, b0, w1, b1, w2, b2, w3, b3,
                                             w4, b4, cw, cb, outp);
}